// Round 3
// baseline (113.734 us; speedup 1.0000x reference)
//
#include <hip/hip_runtime.h>
#include <math.h>

// Chamfer p-norm loss (P=5), B=8, N=M=4096, C=3.
//  - argmin_j |q-r_j|^2 == argmin_j (|r_j|^2/2 - q.r_j); h precomputed at stage.
//  - sum_n pc^5 = sum_n sum_c |q_c - nn_c|^5 -> accumulate fifth powers.
// R3: (1) packed-f32 inner loop: refs paired in LDS as (rx0,rx1)(ry0,ry1)
//     (rz0,rz1)(h0,h1); 3 v_pk_fma_f32 per 2 refs. Argmin index deferred:
//     v_min3 tree over 8-ref groups, track winning group only, exact-equality
//     re-scan of the single winning group after the loop (same fma chain ->
//     bit-identical scores -> first-min tie-break preserved).
//     (2) gather + finalize FUSED into the scan kernel via device-scope
//     atomic counters (last split block per tile gathers; globally-last
//     block finalizes). 3 launches total (2 memsets + 1 kernel).

#define BQ     256            // threads per block = queries per tile
#define SPLITS 4              // ref-dimension splits
#define CH     1024           // refs per split chunk
#define NPAIR  (CH / 2)       // 512 pairs -> 16 KB LDS
#define NGRP   (CH / 8)       // 128 groups of 8 refs

typedef float f32x2 __attribute__((ext_vector_type(2)));

__device__ __forceinline__ unsigned int float_ord(float f) {
    unsigned int u = __float_as_uint(f);
    return (u & 0x80000000u) ? ~u : (u | 0x80000000u);
}

// ws layout: [0,64) acc[16] f32 | [64,1088) tile counters u32[256] |
//            [1088,1092) final counter | [4096, 4096+512K) packed table u64
#define WS_ACC    0
#define WS_TCNT   64
#define WS_FCNT   1088
#define WS_PTAB   4096

__global__ __launch_bounds__(BQ, 4) void chamfer_fused_kernel(
    const float* __restrict__ x, const float* __restrict__ y,
    unsigned char* __restrict__ ws, int N, int M)
{
    __shared__ float4 sref[NPAIR][2];
    __shared__ float red[4];
    __shared__ int s_last;

    float* acc = (float*)(ws + WS_ACC);
    unsigned int* tcnt = (unsigned int*)(ws + WS_TCNT);
    unsigned int* fcnt = (unsigned int*)(ws + WS_FCNT);
    unsigned long long* ptab = (unsigned long long*)(ws + WS_PTAB);

    const int bid   = blockIdx.x;
    const int split = bid & (SPLITS - 1);
    const int qb    = bid / SPLITS;        // 0..255: (b, dir, tile)
    const int tile  = qb & 15;
    const int dir   = (qb >> 4) & 1;
    const int b     = qb >> 5;

    const float* Q;
    const float* R;
    if (dir == 0) { Q = x + (size_t)b * N * 3; R = y + (size_t)b * M * 3; }
    else          { Q = y + (size_t)b * M * 3; R = x + (size_t)b * N * 3; }

    const int tid  = threadIdx.x;
    const int q    = tile * BQ + tid;
    const int base = split * CH;

    // ---- stage CH refs as pairs: [0]=(rx0,rx1,ry0,ry1) [1]=(rz0,rz1,h0,h1)
    for (int p = tid; p < NPAIR; p += BQ) {
        const float* rp = R + (size_t)(base + 2 * p) * 3;
        const float f0 = rp[0], f1 = rp[1], f2 = rp[2];
        const float f3 = rp[3], f4 = rp[4], f5 = rp[5];
        sref[p][0] = make_float4(f0, f3, f1, f4);
        sref[p][1] = make_float4(f2, f5,
                                 0.5f * (f0 * f0 + f1 * f1 + f2 * f2),
                                 0.5f * (f3 * f3 + f4 * f4 + f5 * f5));
    }
    __syncthreads();

    const float qx = Q[q * 3 + 0];
    const float qy = Q[q * 3 + 1];
    const float qz = Q[q * 3 + 2];
    const f32x2 nqx = {-qx, -qx}, nqy = {-qy, -qy}, nqz = {-qz, -qz};

    float best  = 3.4e38f;
    int   bestg = 0;

    #pragma unroll 2
    for (int g = 0; g < NGRP; ++g) {
        const float4* sp = &sref[g * 4][0];
        f32x2 t0, t1, t2, t3;
        {
            const float4 a = sp[0], c = sp[1];
            const f32x2 rx = {a.x, a.y}, ry = {a.z, a.w}, rz = {c.x, c.y}, h = {c.z, c.w};
            t0 = __builtin_elementwise_fma(nqx, rx,
                 __builtin_elementwise_fma(nqy, ry,
                 __builtin_elementwise_fma(nqz, rz, h)));
        }
        {
            const float4 a = sp[2], c = sp[3];
            const f32x2 rx = {a.x, a.y}, ry = {a.z, a.w}, rz = {c.x, c.y}, h = {c.z, c.w};
            t1 = __builtin_elementwise_fma(nqx, rx,
                 __builtin_elementwise_fma(nqy, ry,
                 __builtin_elementwise_fma(nqz, rz, h)));
        }
        {
            const float4 a = sp[4], c = sp[5];
            const f32x2 rx = {a.x, a.y}, ry = {a.z, a.w}, rz = {c.x, c.y}, h = {c.z, c.w};
            t2 = __builtin_elementwise_fma(nqx, rx,
                 __builtin_elementwise_fma(nqy, ry,
                 __builtin_elementwise_fma(nqz, rz, h)));
        }
        {
            const float4 a = sp[6], c = sp[7];
            const f32x2 rx = {a.x, a.y}, ry = {a.z, a.w}, rz = {c.x, c.y}, h = {c.z, c.w};
            t3 = __builtin_elementwise_fma(nqx, rx,
                 __builtin_elementwise_fma(nqy, ry,
                 __builtin_elementwise_fma(nqz, rz, h)));
        }
        // v_min3-friendly tree over the 8 scores
        float m = fminf(fminf(fminf(t0.x, t0.y), fminf(t1.x, t1.y)),
                        fminf(fminf(t2.x, t2.y), fminf(t3.x, t3.y)));
        const bool c = m < best;             // strict <: first group wins ties
        best  = c ? m : best;
        bestg = c ? g : bestg;
    }

    // ---- exact-index re-scan of the single winning 8-ref group
    int bestj = 0;
    {
        const float4* sp = &sref[bestg * 4][0];
        #pragma unroll
        for (int p = 3; p >= 0; --p) {       // descending: smallest j wins
            const float4 a = sp[2 * p], c = sp[2 * p + 1];
            const float thi = fmaf(-qx, a.y, fmaf(-qy, a.w, fmaf(-qz, c.y, c.w)));
            const float tlo = fmaf(-qx, a.x, fmaf(-qy, a.z, fmaf(-qz, c.x, c.z)));
            if (thi == best) bestj = 2 * p + 1;
            if (tlo == best) bestj = 2 * p;
        }
        bestj += bestg * 8 + base;           // ref index within this (b,dir)
    }

    // ---- combine across splits: min over (ordered-score, j) == first-min argmin
    const size_t qidx = (size_t)qb * BQ + tid;
    const unsigned long long pck =
        ((unsigned long long)float_ord(best) << 32) | (unsigned int)bestj;
    atomicMin(&ptab[qidx], pck);

    // ---- handshake: last split block for this tile does the gather
    __syncthreads();
    if (tid == 0) {
        __threadfence();
        const unsigned int old = atomicAdd(&tcnt[qb], 1u);
        s_last = (old == SPLITS - 1);
    }
    __syncthreads();
    if (!s_last) return;

    // ---- gather: read final winners, accumulate fifth powers
    const unsigned long long w = atomicAdd(&ptab[qidx], 0ull);
    const int j = (int)(unsigned int)w;
    const float dx = qx - R[(size_t)j * 3 + 0];
    const float dy = qy - R[(size_t)j * 3 + 1];
    const float dz = qz - R[(size_t)j * 3 + 2];
    const float ax = fabsf(dx), ay = fabsf(dy), az = fabsf(dz);
    const float ax2 = ax * ax, ay2 = ay * ay, az2 = az * az;
    float s = ax2 * ax2 * ax + ay2 * ay2 * ay + az2 * az2 * az;

    #pragma unroll
    for (int off = 32; off > 0; off >>= 1)
        s += __shfl_down(s, off, 64);
    const int wid = tid >> 6, lane = tid & 63;
    if (lane == 0) red[wid] = s;
    __syncthreads();

    if (tid == 0) {
        atomicAdd(&acc[b * 2 + dir], red[0] + red[1] + red[2] + red[3]);
        __threadfence();
        const unsigned int done = atomicAdd(fcnt, 1u);
        if (done == 255u) {                  // globally last tile: finalize
            float total = 0.0f;
            #pragma unroll
            for (int i = 0; i < 16; ++i)
                total += powf(atomicAdd(&acc[i], 0.0f), 0.2f);
            // out pointer stashed in ws? no: written via dedicated param below
            ((float*)(ws - 0))[0] = total;   // placeholder overwritten below
        }
    }
}

// tiny finalize fallback is folded in: the fused kernel writes the scalar via
// a second pass through d_out using a trailing kernel-free trick is fragile,
// so we instead pass d_out directly:
__global__ __launch_bounds__(BQ, 4) void chamfer_fused_kernel_out(
    const float* __restrict__ x, const float* __restrict__ y,
    unsigned char* __restrict__ ws, float* __restrict__ out, int N, int M);

// Re-implement with out param (the version above is not launched).
__global__ __launch_bounds__(BQ, 4) void chamfer_fused2(
    const float* __restrict__ x, const float* __restrict__ y,
    unsigned char* __restrict__ ws, float* __restrict__ out, int N, int M)
{
    __shared__ float4 sref[NPAIR][2];
    __shared__ float red[4];
    __shared__ int s_last;

    float* acc = (float*)(ws + WS_ACC);
    unsigned int* tcnt = (unsigned int*)(ws + WS_TCNT);
    unsigned int* fcnt = (unsigned int*)(ws + WS_FCNT);
    unsigned long long* ptab = (unsigned long long*)(ws + WS_PTAB);

    const int bid   = blockIdx.x;
    const int split = bid & (SPLITS - 1);
    const int qb    = bid / SPLITS;
    const int tile  = qb & 15;
    const int dir   = (qb >> 4) & 1;
    const int b     = qb >> 5;

    const float* Q;
    const float* R;
    if (dir == 0) { Q = x + (size_t)b * N * 3; R = y + (size_t)b * M * 3; }
    else          { Q = y + (size_t)b * M * 3; R = x + (size_t)b * N * 3; }

    const int tid  = threadIdx.x;
    const int q    = tile * BQ + tid;
    const int base = split * CH;

    for (int p = tid; p < NPAIR; p += BQ) {
        const float* rp = R + (size_t)(base + 2 * p) * 3;
        const float f0 = rp[0], f1 = rp[1], f2 = rp[2];
        const float f3 = rp[3], f4 = rp[4], f5 = rp[5];
        sref[p][0] = make_float4(f0, f3, f1, f4);
        sref[p][1] = make_float4(f2, f5,
                                 0.5f * (f0 * f0 + f1 * f1 + f2 * f2),
                                 0.5f * (f3 * f3 + f4 * f4 + f5 * f5));
    }
    __syncthreads();

    const float qx = Q[q * 3 + 0];
    const float qy = Q[q * 3 + 1];
    const float qz = Q[q * 3 + 2];
    const f32x2 nqx = {-qx, -qx}, nqy = {-qy, -qy}, nqz = {-qz, -qz};

    float best  = 3.4e38f;
    int   bestg = 0;

    #pragma unroll 2
    for (int g = 0; g < NGRP; ++g) {
        const float4* sp = &sref[g * 4][0];
        f32x2 t0, t1, t2, t3;
        {
            const float4 a = sp[0], c = sp[1];
            const f32x2 rx = {a.x, a.y}, ry = {a.z, a.w}, rz = {c.x, c.y}, h = {c.z, c.w};
            t0 = __builtin_elementwise_fma(nqx, rx,
                 __builtin_elementwise_fma(nqy, ry,
                 __builtin_elementwise_fma(nqz, rz, h)));
        }
        {
            const float4 a = sp[2], c = sp[3];
            const f32x2 rx = {a.x, a.y}, ry = {a.z, a.w}, rz = {c.x, c.y}, h = {c.z, c.w};
            t1 = __builtin_elementwise_fma(nqx, rx,
                 __builtin_elementwise_fma(nqy, ry,
                 __builtin_elementwise_fma(nqz, rz, h)));
        }
        {
            const float4 a = sp[4], c = sp[5];
            const f32x2 rx = {a.x, a.y}, ry = {a.z, a.w}, rz = {c.x, c.y}, h = {c.z, c.w};
            t2 = __builtin_elementwise_fma(nqx, rx,
                 __builtin_elementwise_fma(nqy, ry,
                 __builtin_elementwise_fma(nqz, rz, h)));
        }
        {
            const float4 a = sp[6], c = sp[7];
            const f32x2 rx = {a.x, a.y}, ry = {a.z, a.w}, rz = {c.x, c.y}, h = {c.z, c.w};
            t3 = __builtin_elementwise_fma(nqx, rx,
                 __builtin_elementwise_fma(nqy, ry,
                 __builtin_elementwise_fma(nqz, rz, h)));
        }
        float m = fminf(fminf(fminf(t0.x, t0.y), fminf(t1.x, t1.y)),
                        fminf(fminf(t2.x, t2.y), fminf(t3.x, t3.y)));
        const bool c = m < best;
        best  = c ? m : best;
        bestg = c ? g : bestg;
    }

    int bestj = 0;
    {
        const float4* sp = &sref[bestg * 4][0];
        #pragma unroll
        for (int p = 3; p >= 0; --p) {
            const float4 a = sp[2 * p], c = sp[2 * p + 1];
            const float thi = fmaf(-qx, a.y, fmaf(-qy, a.w, fmaf(-qz, c.y, c.w)));
            const float tlo = fmaf(-qx, a.x, fmaf(-qy, a.z, fmaf(-qz, c.x, c.z)));
            if (thi == best) bestj = 2 * p + 1;
            if (tlo == best) bestj = 2 * p;
        }
        bestj += bestg * 8 + base;
    }

    const size_t qidx = (size_t)qb * BQ + tid;
    const unsigned long long pck =
        ((unsigned long long)float_ord(best) << 32) | (unsigned int)bestj;
    atomicMin(&ptab[qidx], pck);

    __syncthreads();
    if (tid == 0) {
        __threadfence();
        const unsigned int old = atomicAdd(&tcnt[qb], 1u);
        s_last = (old == SPLITS - 1);
    }
    __syncthreads();
    if (!s_last) return;

    const unsigned long long w = atomicAdd(&ptab[qidx], 0ull);
    const int j = (int)(unsigned int)w;
    const float dx = qx - R[(size_t)j * 3 + 0];
    const float dy = qy - R[(size_t)j * 3 + 1];
    const float dz = qz - R[(size_t)j * 3 + 2];
    const float ax = fabsf(dx), ay = fabsf(dy), az = fabsf(dz);
    const float ax2 = ax * ax, ay2 = ay * ay, az2 = az * az;
    float s = ax2 * ax2 * ax + ay2 * ay2 * ay + az2 * az2 * az;

    #pragma unroll
    for (int off = 32; off > 0; off >>= 1)
        s += __shfl_down(s, off, 64);
    const int wid = tid >> 6, lane = tid & 63;
    if (lane == 0) red[wid] = s;
    __syncthreads();

    if (tid == 0) {
        atomicAdd(&acc[b * 2 + dir], red[0] + red[1] + red[2] + red[3]);
        __threadfence();
        const unsigned int done = atomicAdd(fcnt, 1u);
        if (done == 255u) {
            float total = 0.0f;
            #pragma unroll
            for (int i = 0; i < 16; ++i)
                total += powf(atomicAdd(&acc[i], 0.0f), 0.2f);
            out[0] = total * 0.125f;
        }
    }
}

// ---- round-2 proven fallback (atomicMin table + separate gather/finalize) ----
__device__ __forceinline__ unsigned int float_ord2(float f) { return float_ord(f); }

__global__ __launch_bounds__(BQ) void chamfer_nn_kernel(
    const float* __restrict__ x, const float* __restrict__ y,
    float* __restrict__ acc, int N, int M)
{
    __shared__ float4 sref[2048];
    __shared__ float red[4];
    const int bid  = blockIdx.x;
    const int tile = bid & 15;
    const int dir  = (bid >> 4) & 1;
    const int b    = bid >> 5;
    const float* Q; const float* R; int nr;
    if (dir == 0) { Q = x + (size_t)b * N * 3; R = y + (size_t)b * M * 3; nr = M; }
    else          { Q = y + (size_t)b * M * 3; R = x + (size_t)b * N * 3; nr = N; }
    const int tid = threadIdx.x;
    const int q   = tile * BQ + tid;
    const float qx = Q[q * 3 + 0], qy = Q[q * 3 + 1], qz = Q[q * 3 + 2];
    float best = 3.4e38f; int bestj = 0;
    for (int base = 0; base < nr; base += 2048) {
        __syncthreads();
        for (int j = tid; j < 2048; j += BQ) {
            const float rx = R[(size_t)(base + j) * 3 + 0];
            const float ry = R[(size_t)(base + j) * 3 + 1];
            const float rz = R[(size_t)(base + j) * 3 + 2];
            sref[j] = make_float4(rx, ry, rz, 0.5f * (rx * rx + ry * ry + rz * rz));
        }
        __syncthreads();
        #pragma unroll 8
        for (int j = 0; j < 2048; ++j) {
            const float4 r = sref[j];
            float t = __fmaf_rn(-qx, r.x, r.w);
            t = __fmaf_rn(-qy, r.y, t);
            t = __fmaf_rn(-qz, r.z, t);
            const bool c = t < best;
            best = c ? t : best; bestj = c ? (base + j) : bestj;
        }
    }
    const float dx = qx - R[(size_t)bestj * 3 + 0];
    const float dy = qy - R[(size_t)bestj * 3 + 1];
    const float dz = qz - R[(size_t)bestj * 3 + 2];
    const float ax = fabsf(dx), ay = fabsf(dy), az = fabsf(dz);
    const float ax2 = ax * ax, ay2 = ay * ay, az2 = az * az;
    float s = ax2 * ax2 * ax + ay2 * ay2 * ay + az2 * az2 * az;
    #pragma unroll
    for (int off = 32; off > 0; off >>= 1) s += __shfl_down(s, off, 64);
    const int wid = tid >> 6, lane = tid & 63;
    if (lane == 0) red[wid] = s;
    __syncthreads();
    if (tid == 0) atomicAdd(&acc[b * 2 + dir], red[0] + red[1] + red[2] + red[3]);
}

__global__ void chamfer_finalize_kernel(const float* __restrict__ acc,
                                        float* __restrict__ out)
{
    if (threadIdx.x == 0 && blockIdx.x == 0) {
        float total = 0.0f;
        #pragma unroll
        for (int i = 0; i < 16; ++i) total += powf(acc[i], 0.2f);
        *out = total * 0.125f;
    }
}

extern "C" void kernel_launch(void* const* d_in, const int* in_sizes, int n_in,
                              void* d_out, int out_size, void* d_ws, size_t ws_size,
                              hipStream_t stream)
{
    const float* x = (const float*)d_in[0];
    const float* y = (const float*)d_in[1];
    float* out = (float*)d_out;
    const int N = in_sizes[0] / 24;  // B=8, C=3
    const int M = in_sizes[1] / 24;

    const size_t nQ = (size_t)2 * 8 * N;  // 65536
    const size_t needed = WS_PTAB + nQ * sizeof(unsigned long long);

    if (ws_size >= needed && N == M && N == CH * SPLITS) {
        unsigned char* ws = (unsigned char*)d_ws;
        hipMemsetAsync(ws, 0, 2048, stream);                       // acc + counters
        hipMemsetAsync(ws + WS_PTAB, 0xFF, nQ * 8, stream);        // packed table
        chamfer_fused2<<<256 * SPLITS, BQ, 0, stream>>>(x, y, ws, out, N, M);
    } else {
        float* acc = (float*)d_ws;
        hipMemsetAsync(acc, 0, 16 * sizeof(float), stream);
        chamfer_nn_kernel<<<256, BQ, 0, stream>>>(x, y, acc, N, M);
        chamfer_finalize_kernel<<<1, 64, 0, stream>>>(acc, out);
    }
}